// Round 15
// baseline (51.730 us; speedup 1.0000x reference)
//
#include <hip/hip_runtime.h>
#include <stdint.h>

typedef __attribute__((ext_vector_type(4))) float  f32x4;
typedef __attribute__((ext_vector_type(8))) __bf16 bf16x8;

#define NB   32
#define CC   512
#define DD   512
#define HW   1024
#define NKS  16      // K-steps of 32

#define WAITL()  asm volatile("s_waitcnt lgkmcnt(0)" ::: "memory")
#define BARR()   do { asm volatile("" ::: "memory"); __builtin_amdgcn_s_barrier(); \
                      asm volatile("" ::: "memory"); } while (0)

// Fused softmax + batched GEMM: out[n] = softmax(atts[n]) @ images[n]
// R12 mechanics verbatim, but block = 64 rows x 256 cols, 4 waves ->
// LDS 80KB -> TWO independent blocks/CU: phase-1 / K-loop / epilogue of
// co-resident blocks interleave (the 1-block/CU serialization was the last
// structural exposure). Per-CU MFMA work and exp count unchanged.
__global__ __launch_bounds__(256, 2) void fused_kernel(
        const float* __restrict__ images, const float* __restrict__ atts,
        float* __restrict__ out) {
    __shared__ unsigned short lA[64][512];          // 64KB [row][chunk^row&7]
    __shared__ unsigned short lB[4][4][64][8];      // 16KB wave/kgl planes

    const int b  = blockIdx.x;       // 0..1023
    const int g  = b & 7;            // XCD
    const int q  = b >> 3;           // 0..127
    const int n  = (q & 3) * 8 + g;  // batch, n%8 == XCD
    const int t  = q >> 2;           // 0..31
    const int rt = t & 7;            // row tile 0..7 (64 rows)
    const int ct = t >> 3;           // col tile 0..3 (256 cols)

    const int tid  = threadIdx.x;    // 0..255
    const int lane = tid & 63;
    const int w    = tid >> 6;       // wave 0..3 -> cols ct*256 + w*64
    const int r15  = lane & 15;
    const int kgl  = lane >> 4;

    const float* gAt = atts + (size_t)n * CC * DD + (size_t)(rt * 64) * DD;
    const float* gB  = images + (size_t)n * DD * HW + ct * 256 + w * 64;
    float*       gO  = out + (size_t)n * CC * HW + (size_t)(rt * 64) * HW
                           + ct * 256 + w * 64;

    // ---- phase 1: softmax fill. 16 groups of 16 lanes; 4 rows each ----
    {
        const int grp = tid >> 4;    // 0..15
        const int l16 = tid & 15;
        for (int s = 0; s < 4; ++s) {
            const int row = grp * 4 + s;             // 0..63
            const float* ap = gAt + (size_t)row * DD;
            f32x4 v[8];
            #pragma unroll
            for (int p = 0; p < 4; ++p) {            // chunk q = p*16+l16
                v[2*p]   = *(const f32x4*)(ap + (p * 16 + l16) * 8);
                v[2*p+1] = *(const f32x4*)(ap + (p * 16 + l16) * 8 + 4);
            }
            float m = v[0][0];
            #pragma unroll
            for (int j = 0; j < 8; ++j)
                #pragma unroll
                for (int c = 0; c < 4; ++c) m = fmaxf(m, v[j][c]);
            #pragma unroll
            for (int k = 1; k < 16; k <<= 1) m = fmaxf(m, __shfl_xor(m, k, 16));
            float sum = 0.f;
            #pragma unroll
            for (int j = 0; j < 8; ++j)
                #pragma unroll
                for (int c = 0; c < 4; ++c) {
                    v[j][c] = __expf(v[j][c] - m);
                    sum += v[j][c];
                }
            #pragma unroll
            for (int k = 1; k < 16; k <<= 1) sum += __shfl_xor(sum, k, 16);
            const float inv = 1.0f / sum;
            #pragma unroll
            for (int p = 0; p < 4; ++p) {            // 2-way write banks
                bf16x8 wv;
                #pragma unroll
                for (int e = 0; e < 8; ++e)
                    wv[e] = (__bf16)(v[2*p + (e >> 2)][e & 3] * inv);
                const int slot = (p * 16 + l16) ^ (row & 7);
                *(bf16x8*)&lA[row][slot * 8] = wv;
            }
        }
    }
    WAITL();
    BARR();                          // the ONLY barrier in the kernel

    f32x4 acc[4][4] = {};
    f32x4 bA[8], bB[8];              // two B reg sets (R12 anchor config)

    auto loadB = [&](int kt, f32x4 (&d)[8]) {
        const float* p = gB + (size_t)(kt * 32 + kgl * 8) * HW + r15 * 4;
        #pragma unroll
        for (int j = 0; j < 8; ++j)
            d[j] = *(const f32x4*)(p + (size_t)j * HW);
    };
    // lB plane map: slot(c) = (c&3)*16 + ((c>>2) ^ ((c&3)<<2)); 2-way banks
    auto writeB = [&](const f32x4 (&d)[8]) {
        #pragma unroll
        for (int cc = 0; cc < 4; ++cc) {
            bf16x8 wv;
            #pragma unroll
            for (int j = 0; j < 8; ++j) wv[j] = (__bf16)d[j][cc];
            const int slot = cc * 16 + (r15 ^ (cc << 2));
            *(bf16x8*)&lB[w][kgl][slot][0] = wv;
        }
    };
    auto compute = [&](int kt) {
        bf16x8 af[4], bv[4];
        #pragma unroll
        for (int m = 0; m < 4; ++m) {
            const int slot = ((kt << 2) + kgl) ^ (r15 & 7);
            af[m] = *(const bf16x8*)&lA[m * 16 + r15][slot * 8];
        }
        #pragma unroll
        for (int nf = 0; nf < 4; ++nf) {
            const int c    = nf * 16 + r15;
            const int slot = (c & 3) * 16 + (((c >> 2) ^ ((c & 3) << 2)) & 15);
            bv[nf] = *(const bf16x8*)&lB[w][kgl][slot][0];
        }
        #pragma unroll
        for (int m = 0; m < 4; ++m)
            #pragma unroll
            for (int nf = 0; nf < 4; ++nf)
                acc[m][nf] = __builtin_amdgcn_mfma_f32_16x16x32_bf16(
                    af[m], bv[nf], acc[m][nf], 0, 0, 0);
    };

    // ---- phase 2: barrier-free K-loop (R12 order verbatim) ----
    loadB(0, bA);
    loadB(1, bB);
    writeB(bA);                      // waits bA(0) vmcnt; plane <- tile 0
    #pragma unroll
    for (int kt = 0; kt < NKS; ++kt) {
        compute(kt);                 // plane holds tile kt
        if (kt + 1 < NKS) {
            if (kt & 1) {            // tile kt+1 sits in set[(kt+1)&1]
                writeB(bA);
                if (kt + 2 < NKS) loadB(kt + 2, bB);   // refill consumed set
            } else {
                writeB(bB);
                if (kt + 2 < NKS) loadB(kt + 2, bA);
            }
        }
    }

    // ---- epilogue: C/D layout col=lane&15, row=(lane>>4)*4+r ----
    #pragma unroll
    for (int m = 0; m < 4; ++m)
        #pragma unroll
        for (int nf = 0; nf < 4; ++nf)
            #pragma unroll
            for (int r = 0; r < 4; ++r) {
                const int row = m * 16 + kgl * 4 + r;
                const int col = nf * 16 + r15;
                gO[(size_t)row * HW + col] = acc[m][nf][r];
            }
}

extern "C" void kernel_launch(void* const* d_in, const int* in_sizes, int n_in,
                              void* d_out, int out_size, void* d_ws, size_t ws_size,
                              hipStream_t stream) {
    const float* images = (const float*)d_in[0];
    const float* atts   = (const float*)d_in[1];
    float*       out    = (float*)d_out;

    fused_kernel<<<dim3(NB * 32), dim3(256), 0, stream>>>(images, atts, out);
}

// Round 16
// 40.690 us; speedup vs baseline: 1.2713x; 1.2713x over previous
//
#include <hip/hip_runtime.h>
#include <stdint.h>

typedef __attribute__((ext_vector_type(4))) float  f32x4;
typedef __attribute__((ext_vector_type(8))) __bf16 bf16x8;

#define NB   32
#define CC   512
#define DD   512
#define HW   1024
#define NKS  16      // K-steps of 32

#define WAITL()  asm volatile("s_waitcnt lgkmcnt(0)" ::: "memory")
#define BARR()   do { asm volatile("" ::: "memory"); __builtin_amdgcn_s_barrier(); \
                      asm volatile("" ::: "memory"); } while (0)

// Fused softmax + batched GEMM: out[n] = softmax(atts[n]) @ images[n]
// R12 anchor (34.45us) + ONE isolated change: NONTEMPORAL epilogue stores.
// out (64MB) is write-once/never-read; nt keeps it from evicting the images
// panels the K-loop re-reads 4x from the 4MB per-XCD L2.
__global__ __launch_bounds__(512, 2) void fused_kernel(
        const float* __restrict__ images, const float* __restrict__ atts,
        float* __restrict__ out) {
    __shared__ unsigned short lA[128][512];         // 128KB [row][chunk^row&7]
    __shared__ unsigned short lB[8][4][64][8];      // 32KB  wave/kgl planes

    const int b  = blockIdx.x;       // 0..255
    const int g  = b & 7;            // XCD
    const int q  = b >> 3;           // 0..31
    const int n  = (q & 3) * 8 + g;  // batch, n%8 == XCD
    const int t  = q >> 2;           // 0..7
    const int rt = t & 3;            // row tile 0..3 (128 rows)
    const int ct = t >> 2;           // col tile 0..1 (512 cols)

    const int tid  = threadIdx.x;
    const int lane = tid & 63;
    const int w    = tid >> 6;       // wave 0..7 -> cols ct*512 + w*64
    const int r15  = lane & 15;
    const int kgl  = lane >> 4;

    const float* gAt = atts + (size_t)n * CC * DD + (size_t)(rt * 128) * DD;
    const float* gB  = images + (size_t)n * DD * HW + ct * 512 + w * 64;
    float*       gO  = out + (size_t)n * CC * HW + (size_t)(rt * 128) * HW
                           + ct * 512 + w * 64;

    // ---- phase 1: softmax fill. 32 groups of 16 lanes; 4 rows each ----
    {
        const int grp = tid >> 4;    // 0..31
        const int l16 = tid & 15;
        for (int s = 0; s < 4; ++s) {
            const int row = grp * 4 + s;             // 0..127
            const float* ap = gAt + (size_t)row * DD;
            f32x4 v[8];
            #pragma unroll
            for (int p = 0; p < 4; ++p) {            // chunk q = p*16+l16
                v[2*p]   = *(const f32x4*)(ap + (p * 16 + l16) * 8);
                v[2*p+1] = *(const f32x4*)(ap + (p * 16 + l16) * 8 + 4);
            }
            float m = v[0][0];
            #pragma unroll
            for (int j = 0; j < 8; ++j)
                #pragma unroll
                for (int c = 0; c < 4; ++c) m = fmaxf(m, v[j][c]);
            #pragma unroll
            for (int k = 1; k < 16; k <<= 1) m = fmaxf(m, __shfl_xor(m, k, 16));
            float sum = 0.f;
            #pragma unroll
            for (int j = 0; j < 8; ++j)
                #pragma unroll
                for (int c = 0; c < 4; ++c) {
                    v[j][c] = __expf(v[j][c] - m);
                    sum += v[j][c];
                }
            #pragma unroll
            for (int k = 1; k < 16; k <<= 1) sum += __shfl_xor(sum, k, 16);
            const float inv = 1.0f / sum;
            #pragma unroll
            for (int p = 0; p < 4; ++p) {            // 2-way write banks
                bf16x8 wv;
                #pragma unroll
                for (int e = 0; e < 8; ++e)
                    wv[e] = (__bf16)(v[2*p + (e >> 2)][e & 3] * inv);
                const int slot = (p * 16 + l16) ^ (row & 7);
                *(bf16x8*)&lA[row][slot * 8] = wv;
            }
        }
    }
    WAITL();
    BARR();                          // the ONLY barrier in the kernel

    f32x4 acc[8][4] = {};
    f32x4 bA[8], bB[8];              // two B reg sets

    auto loadB = [&](int kt, f32x4 (&d)[8]) {
        const float* p = gB + (size_t)(kt * 32 + kgl * 8) * HW + r15 * 4;
        #pragma unroll
        for (int j = 0; j < 8; ++j)
            d[j] = *(const f32x4*)(p + (size_t)j * HW);
    };
    // lB plane map: slot(c) = (c&3)*16 + ((c>>2) ^ ((c&3)<<2)); 2-way banks
    auto writeB = [&](const f32x4 (&d)[8]) {
        #pragma unroll
        for (int cc = 0; cc < 4; ++cc) {
            bf16x8 wv;
            #pragma unroll
            for (int j = 0; j < 8; ++j) wv[j] = (__bf16)d[j][cc];
            const int slot = cc * 16 + (r15 ^ (cc << 2));
            *(bf16x8*)&lB[w][kgl][slot][0] = wv;
        }
    };
    auto compute = [&](int kt) {
        bf16x8 af[8], bv[4];
        #pragma unroll
        for (int m = 0; m < 8; ++m) {
            const int slot = ((kt << 2) + kgl) ^ (r15 & 7);
            af[m] = *(const bf16x8*)&lA[m * 16 + r15][slot * 8];
        }
        #pragma unroll
        for (int nf = 0; nf < 4; ++nf) {
            const int c    = nf * 16 + r15;
            const int slot = (c & 3) * 16 + (((c >> 2) ^ ((c & 3) << 2)) & 15);
            bv[nf] = *(const bf16x8*)&lB[w][kgl][slot][0];
        }
        #pragma unroll
        for (int m = 0; m < 8; ++m)
            #pragma unroll
            for (int nf = 0; nf < 4; ++nf)
                acc[m][nf] = __builtin_amdgcn_mfma_f32_16x16x32_bf16(
                    af[m], bv[nf], acc[m][nf], 0, 0, 0);
    };

    // ---- phase 2: barrier-free K-loop (R12 order verbatim) ----
    loadB(0, bA);
    loadB(1, bB);
    writeB(bA);                      // waits bA(0) vmcnt; plane <- tile 0
    #pragma unroll
    for (int kt = 0; kt < NKS; ++kt) {
        compute(kt);                 // plane holds tile kt
        if (kt + 1 < NKS) {
            if (kt & 1) {            // tile kt+1 sits in set[(kt+1)&1]
                writeB(bA);
                if (kt + 2 < NKS) loadB(kt + 2, bB);   // refill consumed set
            } else {
                writeB(bB);
                if (kt + 2 < NKS) loadB(kt + 2, bA);
            }
        }
    }

    // ---- epilogue: nontemporal stores (C/D: col=lane&15, row=(lane>>4)*4+r) ----
    #pragma unroll
    for (int m = 0; m < 8; ++m)
        #pragma unroll
        for (int nf = 0; nf < 4; ++nf)
            #pragma unroll
            for (int r = 0; r < 4; ++r) {
                const int row = m * 16 + kgl * 4 + r;
                const int col = nf * 16 + r15;
                __builtin_nontemporal_store(acc[m][nf][r],
                                            &gO[(size_t)row * HW + col]);
            }
}

extern "C" void kernel_launch(void* const* d_in, const int* in_sizes, int n_in,
                              void* d_out, int out_size, void* d_ws, size_t ws_size,
                              hipStream_t stream) {
    const float* images = (const float*)d_in[0];
    const float* atts   = (const float*)d_in[1];
    float*       out    = (float*)d_out;

    fused_kernel<<<dim3(NB * 8), dim3(512), 0, stream>>>(images, atts, out);
}

// Round 17
// 36.911 us; speedup vs baseline: 1.4015x; 1.1024x over previous
//
#include <hip/hip_runtime.h>
#include <stdint.h>

typedef __attribute__((ext_vector_type(4))) float  f32x4;
typedef __attribute__((ext_vector_type(8))) __bf16 bf16x8;

#define NB   32
#define CC   512
#define DD   512
#define HW   1024
#define NKS  16      // K-steps of 32

#define WAITL()  asm volatile("s_waitcnt lgkmcnt(0)" ::: "memory")
#define BARR()   do { asm volatile("" ::: "memory"); __builtin_amdgcn_s_barrier(); \
                      asm volatile("" ::: "memory"); } while (0)

// Fused softmax + batched GEMM: out[n] = softmax(atts[n]) @ images[n]
// R12 anchor (34.45us) + ONE isolated change: B tiles 0/1 issued BEFORE the
// barrier (the asm memory clobber pins them), landing during the barrier and
// phase-1 tail -> K-loop cold-start latency removed. Everything else verbatim.
__global__ __launch_bounds__(512, 2) void fused_kernel(
        const float* __restrict__ images, const float* __restrict__ atts,
        float* __restrict__ out) {
    __shared__ unsigned short lA[128][512];         // 128KB [row][chunk^row&7]
    __shared__ unsigned short lB[8][4][64][8];      // 32KB  wave/kgl planes

    const int b  = blockIdx.x;       // 0..255
    const int g  = b & 7;            // XCD
    const int q  = b >> 3;           // 0..31
    const int n  = (q & 3) * 8 + g;  // batch, n%8 == XCD
    const int t  = q >> 2;           // 0..7
    const int rt = t & 3;            // row tile 0..3 (128 rows)
    const int ct = t >> 2;           // col tile 0..1 (512 cols)

    const int tid  = threadIdx.x;
    const int lane = tid & 63;
    const int w    = tid >> 6;       // wave 0..7 -> cols ct*512 + w*64
    const int r15  = lane & 15;
    const int kgl  = lane >> 4;

    const float* gAt = atts + (size_t)n * CC * DD + (size_t)(rt * 128) * DD;
    const float* gB  = images + (size_t)n * DD * HW + ct * 512 + w * 64;
    float*       gO  = out + (size_t)n * CC * HW + (size_t)(rt * 128) * HW
                           + ct * 512 + w * 64;

    f32x4 bA[8], bB[8];              // two B reg sets

    auto loadB = [&](int kt, f32x4 (&d)[8]) {
        const float* p = gB + (size_t)(kt * 32 + kgl * 8) * HW + r15 * 4;
        #pragma unroll
        for (int j = 0; j < 8; ++j)
            d[j] = *(const f32x4*)(p + (size_t)j * HW);
    };

    // ---- phase 1: softmax fill. 32 groups of 16 lanes; 4 rows each ----
    {
        const int grp = tid >> 4;    // 0..31
        const int l16 = tid & 15;
        for (int s = 0; s < 4; ++s) {
            const int row = grp * 4 + s;             // 0..127
            const float* ap = gAt + (size_t)row * DD;
            f32x4 v[8];
            #pragma unroll
            for (int p = 0; p < 4; ++p) {            // chunk q = p*16+l16
                v[2*p]   = *(const f32x4*)(ap + (p * 16 + l16) * 8);
                v[2*p+1] = *(const f32x4*)(ap + (p * 16 + l16) * 8 + 4);
            }
            float m = v[0][0];
            #pragma unroll
            for (int j = 0; j < 8; ++j)
                #pragma unroll
                for (int c = 0; c < 4; ++c) m = fmaxf(m, v[j][c]);
            #pragma unroll
            for (int k = 1; k < 16; k <<= 1) m = fmaxf(m, __shfl_xor(m, k, 16));
            float sum = 0.f;
            #pragma unroll
            for (int j = 0; j < 8; ++j)
                #pragma unroll
                for (int c = 0; c < 4; ++c) {
                    v[j][c] = __expf(v[j][c] - m);
                    sum += v[j][c];
                }
            #pragma unroll
            for (int k = 1; k < 16; k <<= 1) sum += __shfl_xor(sum, k, 16);
            const float inv = 1.0f / sum;
            #pragma unroll
            for (int p = 0; p < 4; ++p) {            // 2-way write banks
                bf16x8 wv;
                #pragma unroll
                for (int e = 0; e < 8; ++e)
                    wv[e] = (__bf16)(v[2*p + (e >> 2)][e & 3] * inv);
                const int slot = (p * 16 + l16) ^ (row & 7);
                *(bf16x8*)&lA[row][slot * 8] = wv;
            }
        }
    }
    // pre-barrier B prefetch: pinned before BARR by the asm memory clobber,
    // lands during the barrier wait -> no K-loop cold start
    loadB(0, bA);
    loadB(1, bB);
    WAITL();
    BARR();                          // the ONLY barrier in the kernel

    f32x4 acc[8][4] = {};

    // lB plane map: slot(c) = (c&3)*16 + ((c>>2) ^ ((c&3)<<2)); 2-way banks
    auto writeB = [&](const f32x4 (&d)[8]) {
        #pragma unroll
        for (int cc = 0; cc < 4; ++cc) {
            bf16x8 wv;
            #pragma unroll
            for (int j = 0; j < 8; ++j) wv[j] = (__bf16)d[j][cc];
            const int slot = cc * 16 + (r15 ^ (cc << 2));
            *(bf16x8*)&lB[w][kgl][slot][0] = wv;
        }
    };
    auto compute = [&](int kt) {
        bf16x8 af[8], bv[4];
        #pragma unroll
        for (int m = 0; m < 8; ++m) {
            const int slot = ((kt << 2) + kgl) ^ (r15 & 7);
            af[m] = *(const bf16x8*)&lA[m * 16 + r15][slot * 8];
        }
        #pragma unroll
        for (int nf = 0; nf < 4; ++nf) {
            const int c    = nf * 16 + r15;
            const int slot = (c & 3) * 16 + (((c >> 2) ^ ((c & 3) << 2)) & 15);
            bv[nf] = *(const bf16x8*)&lB[w][kgl][slot][0];
        }
        #pragma unroll
        for (int m = 0; m < 8; ++m)
            #pragma unroll
            for (int nf = 0; nf < 4; ++nf)
                acc[m][nf] = __builtin_amdgcn_mfma_f32_16x16x32_bf16(
                    af[m], bv[nf], acc[m][nf], 0, 0, 0);
    };

    // ---- phase 2: barrier-free K-loop (R12 order verbatim) ----
    writeB(bA);                      // waits bA(0) vmcnt; plane <- tile 0
    #pragma unroll
    for (int kt = 0; kt < NKS; ++kt) {
        compute(kt);                 // plane holds tile kt
        if (kt + 1 < NKS) {
            if (kt & 1) {            // tile kt+1 sits in set[(kt+1)&1]
                writeB(bA);
                if (kt + 2 < NKS) loadB(kt + 2, bB);   // refill consumed set
            } else {
                writeB(bB);
                if (kt + 2 < NKS) loadB(kt + 2, bA);
            }
        }
    }

    // ---- epilogue: C/D layout col=lane&15, row=(lane>>4)*4+r ----
    #pragma unroll
    for (int m = 0; m < 8; ++m)
        #pragma unroll
        for (int nf = 0; nf < 4; ++nf)
            #pragma unroll
            for (int r = 0; r < 4; ++r) {
                const int row = m * 16 + kgl * 4 + r;
                const int col = nf * 16 + r15;
                gO[(size_t)row * HW + col] = acc[m][nf][r];
            }
}

extern "C" void kernel_launch(void* const* d_in, const int* in_sizes, int n_in,
                              void* d_out, int out_size, void* d_ws, size_t ws_size,
                              hipStream_t stream) {
    const float* images = (const float*)d_in[0];
    const float* atts   = (const float*)d_in[1];
    float*       out    = (float*)d_out;

    fused_kernel<<<dim3(NB * 8), dim3(512), 0, stream>>>(images, atts, out);
}